// Round 2
// baseline (235.537 us; speedup 1.0000x reference)
//
#include <hip/hip_runtime.h>

typedef _Float16 f16;
typedef f16 f16x4 __attribute__((ext_vector_type(4)));
typedef f16 f16x8 __attribute__((ext_vector_type(8)));
typedef float f32x4 __attribute__((ext_vector_type(4)));

#define RES 512
#define PTS 128     // mlp: points per block (4 waves x 32 pts)
#define XS  136     // f16 stride, xa main K=128 region (+8 pad)
#define AS  16      // f16 stride, aug region: [nv(8) | bias=1 | zeros(7)]

// R12: sample is L2-line-request bound (~24M L1-miss taps -> ~13.6 line-req/cyc
// per XCD at 84us; VALU 11%, HBM 5% -> nothing else busy). Two fixes:
//  (1) f16 2x2-quad texel layout (8B f16x4 per quad): bilinear footprint needs
//      2 quad-rows, x-adjacent quads share a 64B line ~7/8, y0-even collapses
//      to one quad row -> ~1.5 lines/sample vs ~2.1; f16 halves footprints
//      (m=8 becomes L1-resident; per-XCD L2 hot set ~1.3MB).
//  (2) cost-balanced plane->XCD map: expensive planes (L1-missing, m=9..31, 23
//      total) spread 3/3/3/3/3/3/3/2 (groups 0-6: {g,g+9,g+17,g+25}; group 7:
//      {7,8,16,24}) vs old 1.5x imbalance. nv slot(m)=(m&7)*4+(m>>3) kept ->
//      mlp untouched.
// f16 tap semantics = R10-passing TT=f16 variant (same absmax); index/lerp
// chain verbatim. ws fallback keeps R11 f32 path if quad buffer doesn't fit.

// ---------------------------------------------------------------- pack kernels
__global__ __launch_bounds__(256)
void pack_quad_k(const float* __restrict__ n, f16* __restrict__ q) {
    // one thread per 2x2 quad: quad(m,qy,qx) = {t(2qy,2qx),t(2qy,2qx+1),
    //                                           t(2qy+1,2qx),t(2qy+1,2qx+1)}
    const int idx = blockIdx.x * 256 + threadIdx.x;
    const int qx = idx & 255, rest = idx >> 8;
    const int qy = rest & 255, m = rest >> 8;
    const float* src = n + ((size_t)m * 512 + 2 * qy) * 512 + 2 * qx;
    const float2 r0 = *(const float2*)(src);
    const float2 r1 = *(const float2*)(src + 512);
    f16x4 o; o[0]=(f16)r0.x; o[1]=(f16)r0.y; o[2]=(f16)r1.x; o[3]=(f16)r1.y;
    *(f16x4*)(q + (size_t)idx * 4) = o;
}

__global__ __launch_bounds__(256)
void pack_w_k(const float* __restrict__ lw,  const float* __restrict__ lnw,
              const float* __restrict__ lb,  const float* __restrict__ tw1,
              const float* __restrict__ tb1,
              f16* __restrict__ wf, f16* __restrict__ waugf) {
    const int g = blockIdx.x * 256 + threadIdx.x;
    if (g < 10240) {            // Wm fragments: 5 layers x 32 frags x 64 lanes
        const int L = g >> 11, r = g & 2047;
        const int lane = r & 63, frag = r >> 6;
        const int q = lane >> 4, l15 = lane & 15;
        const int mt = frag >> 2, c = frag & 3;
        const float* src = ((L < 4) ? (lw + L * 16384) : tw1)
                           + (mt * 16 + l15) * 128 + c * 32 + q * 8;
        f16x8 h;
        #pragma unroll
        for (int j = 0; j < 8; ++j) h[j] = (f16)src[j];
        *(f16x8*)(wf + (size_t)g * 8) = h;
    } else {                    // Waug fragments: 5 layers x 8 frags x 64 lanes
        const int ga = g - 10240;            // < 2560
        const int L = ga >> 9, r = ga & 511;
        const int lane = r & 63, mt = r >> 6;
        const int q = lane >> 4, l15 = lane & 15;
        const int row = mt * 16 + l15;
        f16x8 h = {};
        if (q == 0 && L < 4) {               // k=0..7: lnw slice
            const float* src = lnw + L * 1024 + row * 8;
            #pragma unroll
            for (int j = 0; j < 8; ++j) h[j] = (f16)src[j];
        }
        if (q == 1)                          // k=8: bias
            h[0] = (f16)((L < 4) ? lb[L * 128 + row] : tb1[row]);
        *(f16x8*)(waugf + (size_t)ga * 8) = h;
    }
}

// ---------------------------------------------------------------- sample kernel
__device__ __forceinline__ float quad_tap(uint2 q, int sy, int sx) {
    unsigned w = sy ? q.y : q.x;          // row select within quad
    w >>= (sx << 4);                      // col select (low/high half)
    union { unsigned short u; f16 h; } cv; cv.u = (unsigned short)w;
    return (float)cv.h;
}

template <bool QUAD>
__global__ __launch_bounds__(256, 8)
void sample_kernel(const void* __restrict__ noise_v,
                   const float* __restrict__ coords,
                   const float* __restrict__ trans,
                   f16* __restrict__ nv_ws, const int Ntot)
{
    __shared__ float T_sh[128];
    const int t = threadIdx.x;
    if (t < 128) T_sh[t] = trans[t];
    __syncthreads();

    const int g = blockIdx.x & 7;              // feature group -> XCD pin
    const int p = (blockIdx.x >> 3) * 256 + t; // point id

    // cost-balanced plane sets (expensive planes m=9..31 split 3/..3/2)
    int mk[4];
    if (g < 7) { mk[0] = g; mk[1] = g + 9; mk[2] = g + 17; mk[3] = g + 25; }
    else       { mk[0] = 7; mk[1] = 8;     mk[2] = 16;     mk[3] = 24;     }

    const float2 c2 = *(const float2*)(coords + p * 2);

    float nvr[4];
    {
        #pragma clang fp contract(off)
        const float cx = c2.x;
        const float cy = c2.y;
        #pragma unroll
        for (int k = 0; k < 4; ++k) {
            const int m = mk[k];
            const float T00 = T_sh[m*4+0], T01 = T_sh[m*4+1];
            const float T10 = T_sh[m*4+2], T11 = T_sh[m*4+3];
            const float p0x = T00 * cx;                       // k=0: fl(cx*T00)
            const float p0y = T10 * cx;
            const float ncx = __builtin_fmaf(T01, cy, p0x);   // k=1: fused accumulate
            const float ncy = __builtin_fmaf(T11, cy, p0y);
            const float u = ncx - 0.5f;
            const float v = ncy - 0.5f;
            const float xf = floorf(u), yf = floorf(v);
            const float xw = u - xf, yw = v - yf;
            int ix = (xf >= 2147483648.0f || xf < -2147483648.0f) ? (int)(-2147483647 - 1) : (int)xf;
            int iy = (yf >= 2147483648.0f || yf < -2147483648.0f) ? (int)(-2147483647 - 1) : (int)yf;
            const int x0 = ix & (RES - 1);
            const int x1 = (int)(((unsigned)ix + 1u) & (unsigned)(RES - 1));
            const int y0 = iy & (RES - 1);
            const int y1 = (int)(((unsigned)iy + 1u) & (unsigned)(RES - 1));
            float i00, i01, i10, i11;
            if constexpr (QUAD) {
                const f16* pl = (const f16*)noise_v + (size_t)m * (256 * 256 * 4);
                const int qx0 = x0 >> 1, sx0 = x0 & 1;
                const int qx1 = x1 >> 1, sx1 = x1 & 1;
                const int qy0 = y0 >> 1, sy0 = y0 & 1;
                const int qy1 = y1 >> 1, sy1 = y1 & 1;
                const uint2 qa = *(const uint2*)(pl + (qy0 * 256 + qx0) * 4);
                const uint2 qb = *(const uint2*)(pl + (qy0 * 256 + qx1) * 4);
                const uint2 qc = *(const uint2*)(pl + (qy1 * 256 + qx0) * 4);
                const uint2 qd = *(const uint2*)(pl + (qy1 * 256 + qx1) * 4);
                i00 = quad_tap(qa, sy0, sx0);
                i01 = quad_tap(qb, sy0, sx1);
                i10 = quad_tap(qc, sy1, sx0);
                i11 = quad_tap(qd, sy1, sx1);
            } else {
                const float* pl = (const float*)noise_v + (size_t)m * (RES * RES);
                i00 = pl[y0 * RES + x0];
                i01 = pl[y0 * RES + x1];
                i10 = pl[y1 * RES + x0];
                i11 = pl[y1 * RES + x1];
            }
            const float a0 = i00 + (i01 - i00) * xw;
            const float a1 = i10 + (i11 - i10) * xw;
            nvr[k] = a0 + (a1 - a0) * yw;
        }
    }
    #pragma unroll
    for (int k = 0; k < 4; ++k) {              // nv slot(m) = (m&7)*4 + (m>>3)
        const int m = mk[k];
        const int slot = (m & 7) * 4 + (m >> 3);
        nv_ws[(size_t)slot * Ntot + p] = (f16)nvr[k];
    }
}

// ---------------------------------------------------------------- mlp kernel
__global__ __launch_bounds__(256, 2)
void mlp_kernel(const f16* __restrict__ nv_ws,
                const f16* __restrict__ wf,
                const f16* __restrict__ waugf,
                const float* __restrict__ input_vec,
                const float* __restrict__ tw2,
                const float* __restrict__ tb2,
                float* __restrict__ out, const int Ntot)
{
    __shared__ f16 Wm[16384];           // 32 frags x 512 f16 = 32768 B, lane-linear
    __shared__ f16 Waug[4096];          //  8 frags x 512 f16 =  8192 B
    __shared__ f16 xa[PTS * XS];        // 34816 B
    __shared__ f16 xaug[PTS * AS];      //  4096 B
    __shared__ __align__(16) float tw2_sh[128];

    const int t    = threadIdx.x;
    const int wave = t >> 6;
    const int lane = t & 63;
    const int q    = lane >> 4;
    const int l15  = lane & 15;
    const int pbase = blockIdx.x * PTS;
    const int pw    = wave * 32;        // wave-private point rows [pw, pw+32)
    const int p = t >> 1, h = t & 1;    // 2 threads per point (nv ownership)

    // ---------------- init ----------------
    if (t < 128) {
        tw2_sh[t] = tw2[t];
        xaug[t * AS + 8] = (f16)1.0f;          // bias lane
        #pragma unroll
        for (int c = 9; c < 16; ++c) xaug[t * AS + c] = (f16)0.0f;
    }
    {   // xa rows = input_vec (f16); thread (p,h) fills its point's half-row
        #pragma unroll
        for (int j = 0; j < 8; ++j) {
            const float4 a = ((const float4*)input_vec)[h * 16 + j * 2];
            const float4 b = ((const float4*)input_vec)[h * 16 + j * 2 + 1];
            f16x8 hv;
            hv[0]=(f16)a.x; hv[1]=(f16)a.y; hv[2]=(f16)a.z; hv[3]=(f16)a.w;
            hv[4]=(f16)b.x; hv[5]=(f16)b.y; hv[6]=(f16)b.z; hv[7]=(f16)b.w;
            *(f16x8*)&xa[p * XS + h * 64 + j * 8] = hv;
        }
    }
    const float tb2_0 = tb2[0];

    // nv for this thread's point/half: feat 16h+j lives in plane j*4+2h,
    // feat 16h+8+j in plane j*4+2h+1; coalesced scalar loads (consecutive p).
    f16x8 nva, nvb;
    {
        const int P = pbase + p;
        #pragma unroll
        for (int j = 0; j < 8; ++j) {
            nva[j] = nv_ws[(size_t)(j * 4 + 2 * h)     * Ntot + P];
            nvb[j] = nv_ws[(size_t)(j * 4 + 2 * h + 1) * Ntot + P];
        }
    }
    if (h == 0) *(f16x8*)&xaug[p * AS] = nva;   // layer-0 feats 0..7 (same-wave reader)

    // ---------------- 5 MFMA layers ----------------
    f32x4 acc[2][8];
    #pragma unroll 1
    for (int L = 0; L < 5; ++L) {
        __syncthreads();   // all waves done reading previous Wm/Waug
        {   // stage W fragments: straight f16 copy, lane-linear both sides
            const f16* wsrc = wf + L * 16384;
            #pragma unroll
            for (int i = 0; i < 8; ++i) {
                const int idx = t + i * 256;
                *(f16x8*)&Wm[idx * 8] = *(const f16x8*)&wsrc[idx * 8];
            }
            const f16* asrc = waugf + L * 4096;
            *(f16x8*)&Waug[t * 8]         = *(const f16x8*)&asrc[t * 8];
            *(f16x8*)&Waug[(t + 256) * 8] = *(const f16x8*)&asrc[(t + 256) * 8];
        }
        __syncthreads();

        {
            const f32x4 z4 = {0.f, 0.f, 0.f, 0.f};
            #pragma unroll
            for (int i = 0; i < 2; ++i)
                #pragma unroll
                for (int mt = 0; mt < 8; ++mt) acc[i][mt] = z4;
        }
        const int pr0 = (pw + l15) * XS, pr1 = (pw + 16 + l15) * XS;
        #pragma unroll
        for (int c = 0; c < 4; ++c) {   // main K=128
            const int kc = c * 32 + q * 8;
            const f16x8 xb0 = *(const f16x8*)&xa[pr0 + kc];
            const f16x8 xb1 = *(const f16x8*)&xa[pr1 + kc];
            #pragma unroll
            for (int mt = 0; mt < 8; ++mt) {
                const f16x8 aw = *(const f16x8*)&Wm[((mt * 4 + c) * 64 + lane) * 8]; // conflict-free
                acc[0][mt] = __builtin_amdgcn_mfma_f32_16x16x32_f16(aw, xb0, acc[0][mt], 0, 0, 0);
                acc[1][mt] = __builtin_amdgcn_mfma_f32_16x16x32_f16(aw, xb1, acc[1][mt], 0, 0, 0);
            }
        }
        {   // aug chunk: A-side fully stored (zeros for q>=2), B-side exec-masked
            f16x8 xb0 = {}, xb1 = {};
            if (q < 2) {
                xb0 = *(const f16x8*)&xaug[(pw + l15) * AS + q * 8];
                xb1 = *(const f16x8*)&xaug[(pw + 16 + l15) * AS + q * 8];
            }
            #pragma unroll
            for (int mt = 0; mt < 8; ++mt) {
                const f16x8 aw = *(const f16x8*)&Waug[(mt * 64 + lane) * 8];
                acc[0][mt] = __builtin_amdgcn_mfma_f32_16x16x32_f16(aw, xb0, acc[0][mt], 0, 0, 0);
                acc[1][mt] = __builtin_amdgcn_mfma_f32_16x16x32_f16(aw, xb1, acc[1][mt], 0, 0, 0);
            }
        }

        if (L < 4) {
            // epilogue: leaky-relu + pack; wave-private xa rows -> no barrier
            #pragma unroll
            for (int i = 0; i < 2; ++i) {
                const int pr = (pw + i * 16 + l15) * XS;
                #pragma unroll
                for (int mt = 0; mt < 8; ++mt) {
                    f16x4 hv;
                    #pragma unroll
                    for (int r = 0; r < 4; ++r) {
                        float v = acc[i][mt][r];
                        v = fmaxf(v, 0.01f * v);
                        hv[r] = (f16)v;
                    }
                    *(f16x4*)&xa[pr + mt * 16 + q * 4] = hv;
                }
            }
            if (L < 3) {   // next layer's nv into xaug (owning thread; same-wave reader)
                const int Ln = L + 1;
                if ((Ln >> 1) == h)
                    *(f16x8*)&xaug[p * AS] = (Ln & 1) ? nvb : nva;
            }
        } else {
            // head: out = tw2 . lrelu(h) + tb2; butterfly over quads
            #pragma unroll
            for (int i = 0; i < 2; ++i) {
                float s = 0.f;
                #pragma unroll
                for (int mt = 0; mt < 8; ++mt) {
                    const f32x4 w4 = *(const f32x4*)&tw2_sh[mt * 16 + q * 4];
                    #pragma unroll
                    for (int r = 0; r < 4; ++r) {
                        float v = acc[i][mt][r];
                        v = fmaxf(v, 0.01f * v);
                        s += w4[r] * v;
                    }
                }
                s += __shfl_xor(s, 16);
                s += __shfl_xor(s, 32);
                if (q == 0) out[pbase + pw + i * 16 + l15] = s + tb2_0;
            }
        }
    }
}

extern "C" void kernel_launch(void* const* d_in, const int* in_sizes, int n_in,
                              void* d_out, int out_size, void* d_ws, size_t ws_size,
                              hipStream_t stream) {
    const float* noise  = (const float*)d_in[0];
    const float* coords = (const float*)d_in[1];
    const float* trans  = (const float*)d_in[2];
    const float* ivec   = (const float*)d_in[3];
    const float* lw     = (const float*)d_in[4];
    const float* lb     = (const float*)d_in[5];
    const float* lnw    = (const float*)d_in[6];
    const float* tw1    = (const float*)d_in[7];
    const float* tb1    = (const float*)d_in[8];
    const float* tw2    = (const float*)d_in[9];
    const float* tb2    = (const float*)d_in[10];
    float* o            = (float*)d_out;

    const int N = in_sizes[1] / 2;                    // coords is [N,2]
    // ws layout: nv [32 planes][N] f16 (16 MiB) | wf | waug | quads (16 MiB)
    f16* nv    = (f16*)d_ws;
    const size_t NV = (size_t)N * 32;                 // f16 units
    f16* wfp   = nv + NV;
    f16* waugp = wfp + 5 * 16384;
    f16* qn    = waugp + 5 * 4096;
    const size_t need_full = (NV + 5 * 16384 + 5 * 4096
                              + (size_t)32 * 256 * 256 * 4) * sizeof(f16);

    pack_w_k<<<50, 256, 0, stream>>>(lw, lnw, lb, tw1, tb1, wfp, waugp);
    if (ws_size >= need_full) {   // ws_size constant across calls -> graph-safe
        pack_quad_k<<<(32 * 256 * 256) / 256, 256, 0, stream>>>(noise, qn);
        sample_kernel<true><<<(N / 256) * 8, 256, 0, stream>>>(qn, coords, trans, nv, N);
    } else {
        sample_kernel<false><<<(N / 256) * 8, 256, 0, stream>>>(noise, coords, trans, nv, N);
    }
    mlp_kernel<<<N / PTS, 256, 0, stream>>>(nv, wfp, waugp, ivec, tw2, tb2, o, N);
}

// Round 3
// 223.768 us; speedup vs baseline: 1.0526x; 1.0526x over previous
//
#include <hip/hip_runtime.h>

typedef _Float16 f16;
typedef f16 f16x4 __attribute__((ext_vector_type(4)));
typedef f16 f16x8 __attribute__((ext_vector_type(8)));
typedef float f32x4 __attribute__((ext_vector_type(4)));

#define RES 512
#define PTS 128     // mlp: points per block (4 waves x 32 pts)
#define XS  138     // f16 stride: 69 dwords == 5 mod 32 (odd) -> <=3-way banks
#define AS  18      // f16 stride, aug region: 9 dwords (odd) -> ~2-way banks

// R13: mlp was the leader (80.8us; MfmaUtil 27, VALU 33, occ 19.7, 3.96M LDS
// conflicts). Two fixes:
//  (1) XS 136->138, AS 16->18: old stride 68 dw == 4 mod 32 made every xb
//      ds_read_b128 an 8-way bank conflict (410K reads x ~9.7cyc == the 3.96M
//      counter). Odd dword strides cap at ~3-way (mostly 2-way = free).
//  (2) layer-0 main GEMM folded to a constant: L0 input = input_vec for ALL
//      points, so c0 = lw0@ivec + lb0 is precomputed (f32) in the pack kernel
//      and stored as L0's Waug bias row. L0 becomes aug-only: -64/400 MFMAs
//      per wave, no Wm[0] staging, no input_vec->xa init (L0 epilogue writes
//      all of xa).
// Also merged pack_quad+pack_w+c0 into one dispatch. Sample kernel unchanged
// from R12 (quad texels + balanced XCD pinning).

// ---------------------------------------------------------------- pack kernels
__device__ __forceinline__
void pack_w_body(int g, const float* __restrict__ lw, const float* __restrict__ lnw,
                 const float* __restrict__ lb, const float* __restrict__ tw1,
                 const float* __restrict__ tb1, const float* __restrict__ ivec,
                 f16* __restrict__ wf, f16* __restrict__ waugf) {
    if (g < 10240) {            // Wm fragments: 5 layers x 32 frags x 64 lanes
        const int L = g >> 11, r = g & 2047;
        const int lane = r & 63, frag = r >> 6;
        const int q = lane >> 4, l15 = lane & 15;
        const int mt = frag >> 2, c = frag & 3;
        const float* src = ((L < 4) ? (lw + L * 16384) : tw1)
                           + (mt * 16 + l15) * 128 + c * 32 + q * 8;
        f16x8 h;
        #pragma unroll
        for (int j = 0; j < 8; ++j) h[j] = (f16)src[j];
        *(f16x8*)(wf + (size_t)g * 8) = h;
    } else {                    // Waug fragments: 5 layers x 8 frags x 64 lanes
        const int ga = g - 10240;            // < 2560
        const int L = ga >> 9, r = ga & 511;
        const int lane = r & 63, mt = r >> 6;
        const int q = lane >> 4, l15 = lane & 15;
        const int row = mt * 16 + l15;
        f16x8 h = {};
        if (q == 0 && L < 4) {               // k=0..7: lnw slice
            const float* src = lnw + L * 1024 + row * 8;
            #pragma unroll
            for (int j = 0; j < 8; ++j) h[j] = (f16)src[j];
        }
        if (q == 1) {                        // k=8: bias (L0: + lw0@ivec const)
            if (L == 0) {
                float s = lb[row];
                const float4* w4 = (const float4*)(lw + row * 128);
                const float4* v4 = (const float4*)ivec;
                #pragma unroll 8
                for (int k = 0; k < 32; ++k) {
                    const float4 w = w4[k], v = v4[k];
                    s += w.x * v.x + w.y * v.y + w.z * v.z + w.w * v.w;
                }
                h[0] = (f16)s;
            } else {
                h[0] = (f16)((L < 4) ? lb[L * 128 + row] : tb1[row]);
            }
        }
        *(f16x8*)(waugf + (size_t)ga * 8) = h;
    }
}

__global__ __launch_bounds__(256)
void pack_all_k(const float* __restrict__ n, f16* __restrict__ q,
                const float* __restrict__ lw,  const float* __restrict__ lnw,
                const float* __restrict__ lb,  const float* __restrict__ tw1,
                const float* __restrict__ tb1, const float* __restrict__ ivec,
                f16* __restrict__ wf, f16* __restrict__ waugf) {
    const int b = blockIdx.x;
    if (b < 8192) {   // quad packing: one thread per 2x2 texel quad
        const int idx = b * 256 + threadIdx.x;
        const int qx = idx & 255, rest = idx >> 8;
        const int qy = rest & 255, m = rest >> 8;
        const float* src = n + ((size_t)m * 512 + 2 * qy) * 512 + 2 * qx;
        const float2 r0 = *(const float2*)(src);
        const float2 r1 = *(const float2*)(src + 512);
        f16x4 o; o[0]=(f16)r0.x; o[1]=(f16)r0.y; o[2]=(f16)r1.x; o[3]=(f16)r1.y;
        *(f16x4*)(q + (size_t)idx * 4) = o;
    } else {
        pack_w_body((b - 8192) * 256 + threadIdx.x, lw, lnw, lb, tw1, tb1, ivec, wf, waugf);
    }
}

__global__ __launch_bounds__(256)
void pack_w_k(const float* __restrict__ lw,  const float* __restrict__ lnw,
              const float* __restrict__ lb,  const float* __restrict__ tw1,
              const float* __restrict__ tb1, const float* __restrict__ ivec,
              f16* __restrict__ wf, f16* __restrict__ waugf) {
    pack_w_body(blockIdx.x * 256 + threadIdx.x, lw, lnw, lb, tw1, tb1, ivec, wf, waugf);
}

// ---------------------------------------------------------------- sample kernel
__device__ __forceinline__ float quad_tap(uint2 q, int sy, int sx) {
    unsigned w = sy ? q.y : q.x;          // row select within quad
    w >>= (sx << 4);                      // col select (low/high half)
    union { unsigned short u; f16 h; } cv; cv.u = (unsigned short)w;
    return (float)cv.h;
}

template <bool QUAD>
__global__ __launch_bounds__(256, 8)
void sample_kernel(const void* __restrict__ noise_v,
                   const float* __restrict__ coords,
                   const float* __restrict__ trans,
                   f16* __restrict__ nv_ws, const int Ntot)
{
    __shared__ float T_sh[128];
    const int t = threadIdx.x;
    if (t < 128) T_sh[t] = trans[t];
    __syncthreads();

    const int g = blockIdx.x & 7;              // feature group -> XCD pin
    const int p = (blockIdx.x >> 3) * 256 + t; // point id

    // cost-balanced plane sets (expensive planes m=9..31 split 3/..3/2)
    int mk[4];
    if (g < 7) { mk[0] = g; mk[1] = g + 9; mk[2] = g + 17; mk[3] = g + 25; }
    else       { mk[0] = 7; mk[1] = 8;     mk[2] = 16;     mk[3] = 24;     }

    const float2 c2 = *(const float2*)(coords + p * 2);

    float nvr[4];
    {
        #pragma clang fp contract(off)
        const float cx = c2.x;
        const float cy = c2.y;
        #pragma unroll
        for (int k = 0; k < 4; ++k) {
            const int m = mk[k];
            const float T00 = T_sh[m*4+0], T01 = T_sh[m*4+1];
            const float T10 = T_sh[m*4+2], T11 = T_sh[m*4+3];
            const float p0x = T00 * cx;                       // k=0: fl(cx*T00)
            const float p0y = T10 * cx;
            const float ncx = __builtin_fmaf(T01, cy, p0x);   // k=1: fused accumulate
            const float ncy = __builtin_fmaf(T11, cy, p0y);
            const float u = ncx - 0.5f;
            const float v = ncy - 0.5f;
            const float xf = floorf(u), yf = floorf(v);
            const float xw = u - xf, yw = v - yf;
            int ix = (xf >= 2147483648.0f || xf < -2147483648.0f) ? (int)(-2147483647 - 1) : (int)xf;
            int iy = (yf >= 2147483648.0f || yf < -2147483648.0f) ? (int)(-2147483647 - 1) : (int)yf;
            const int x0 = ix & (RES - 1);
            const int x1 = (int)(((unsigned)ix + 1u) & (unsigned)(RES - 1));
            const int y0 = iy & (RES - 1);
            const int y1 = (int)(((unsigned)iy + 1u) & (unsigned)(RES - 1));
            float i00, i01, i10, i11;
            if constexpr (QUAD) {
                const f16* pl = (const f16*)noise_v + (size_t)m * (256 * 256 * 4);
                const int qx0 = x0 >> 1, sx0 = x0 & 1;
                const int qx1 = x1 >> 1, sx1 = x1 & 1;
                const int qy0 = y0 >> 1, sy0 = y0 & 1;
                const int qy1 = y1 >> 1, sy1 = y1 & 1;
                const uint2 qa = *(const uint2*)(pl + (qy0 * 256 + qx0) * 4);
                const uint2 qb = *(const uint2*)(pl + (qy0 * 256 + qx1) * 4);
                const uint2 qc = *(const uint2*)(pl + (qy1 * 256 + qx0) * 4);
                const uint2 qd = *(const uint2*)(pl + (qy1 * 256 + qx1) * 4);
                i00 = quad_tap(qa, sy0, sx0);
                i01 = quad_tap(qb, sy0, sx1);
                i10 = quad_tap(qc, sy1, sx0);
                i11 = quad_tap(qd, sy1, sx1);
            } else {
                const float* pl = (const float*)noise_v + (size_t)m * (RES * RES);
                i00 = pl[y0 * RES + x0];
                i01 = pl[y0 * RES + x1];
                i10 = pl[y1 * RES + x0];
                i11 = pl[y1 * RES + x1];
            }
            const float a0 = i00 + (i01 - i00) * xw;
            const float a1 = i10 + (i11 - i10) * xw;
            nvr[k] = a0 + (a1 - a0) * yw;
        }
    }
    #pragma unroll
    for (int k = 0; k < 4; ++k) {              // nv slot(m) = (m&7)*4 + (m>>3)
        const int m = mk[k];
        const int slot = (m & 7) * 4 + (m >> 3);
        nv_ws[(size_t)slot * Ntot + p] = (f16)nvr[k];
    }
}

// ---------------------------------------------------------------- mlp kernel
__global__ __launch_bounds__(256, 2)
void mlp_kernel(const f16* __restrict__ nv_ws,
                const f16* __restrict__ wf,
                const f16* __restrict__ waugf,
                const float* __restrict__ tw2,
                const float* __restrict__ tb2,
                float* __restrict__ out, const int Ntot)
{
    __shared__ f16 Wm[16384];           // 32 frags x 512 f16 = 32768 B, lane-linear
    __shared__ f16 Waug[4096];          //  8 frags x 512 f16 =  8192 B
    __shared__ f16 xa[PTS * XS];        // 35328 B
    __shared__ f16 xaug[PTS * AS];      //  4608 B
    __shared__ __align__(16) float tw2_sh[128];

    const int t    = threadIdx.x;
    const int wave = t >> 6;
    const int lane = t & 63;
    const int q    = lane >> 4;
    const int l15  = lane & 15;
    const int pbase = blockIdx.x * PTS;
    const int pw    = wave * 32;        // wave-private point rows [pw, pw+32)
    const int p = t >> 1, h = t & 1;    // 2 threads per point (nv ownership)

    // ---------------- init ----------------
    if (t < 128) {
        tw2_sh[t] = tw2[t];
        xaug[t * AS + 8] = (f16)1.0f;          // bias lane
        #pragma unroll
        for (int c = 9; c < 16; ++c) xaug[t * AS + c] = (f16)0.0f;
    }
    const float tb2_0 = tb2[0];

    // nv for this thread's point/half: feat 16h+j lives in plane j*4+2h,
    // feat 16h+8+j in plane j*4+2h+1; coalesced scalar loads (consecutive p).
    f16x8 nva, nvb;
    {
        const int P = pbase + p;
        #pragma unroll
        for (int j = 0; j < 8; ++j) {
            nva[j] = nv_ws[(size_t)(j * 4 + 2 * h)     * Ntot + P];
            nvb[j] = nv_ws[(size_t)(j * 4 + 2 * h + 1) * Ntot + P];
        }
    }
    if (h == 0) *(f16x8*)&xaug[p * AS] = nva;   // layer-0 feats 0..7 (same-wave reader)

    // ---------------- 5 MFMA layers (L0 = aug-only; main folded into c0) ----
    f32x4 acc[2][8];
    #pragma unroll 1
    for (int L = 0; L < 5; ++L) {
        __syncthreads();   // all waves done reading previous Wm/Waug
        {   // stage W fragments: straight f16 copy, lane-linear both sides
            if (L) {
                const f16* wsrc = wf + L * 16384;
                #pragma unroll
                for (int i = 0; i < 8; ++i) {
                    const int idx = t + i * 256;
                    *(f16x8*)&Wm[idx * 8] = *(const f16x8*)&wsrc[idx * 8];
                }
            }
            const f16* asrc = waugf + L * 4096;
            *(f16x8*)&Waug[t * 8]         = *(const f16x8*)&asrc[t * 8];
            *(f16x8*)&Waug[(t + 256) * 8] = *(const f16x8*)&asrc[(t + 256) * 8];
        }
        __syncthreads();

        {
            const f32x4 z4 = {0.f, 0.f, 0.f, 0.f};
            #pragma unroll
            for (int i = 0; i < 2; ++i)
                #pragma unroll
                for (int mt = 0; mt < 8; ++mt) acc[i][mt] = z4;
        }
        if (L) {
            const int pr0 = (pw + l15) * XS, pr1 = (pw + 16 + l15) * XS;
            #pragma unroll
            for (int c = 0; c < 4; ++c) {   // main K=128
                const int kc = c * 32 + q * 8;
                const f16x8 xb0 = *(const f16x8*)&xa[pr0 + kc];
                const f16x8 xb1 = *(const f16x8*)&xa[pr1 + kc];
                #pragma unroll
                for (int mt = 0; mt < 8; ++mt) {
                    const f16x8 aw = *(const f16x8*)&Wm[((mt * 4 + c) * 64 + lane) * 8]; // conflict-free
                    acc[0][mt] = __builtin_amdgcn_mfma_f32_16x16x32_f16(aw, xb0, acc[0][mt], 0, 0, 0);
                    acc[1][mt] = __builtin_amdgcn_mfma_f32_16x16x32_f16(aw, xb1, acc[1][mt], 0, 0, 0);
                }
            }
        }
        {   // aug chunk: A-side fully stored (zeros for q>=2), B-side exec-masked
            f16x8 xb0 = {}, xb1 = {};
            if (q < 2) {
                xb0 = *(const f16x8*)&xaug[(pw + l15) * AS + q * 8];
                xb1 = *(const f16x8*)&xaug[(pw + 16 + l15) * AS + q * 8];
            }
            #pragma unroll
            for (int mt = 0; mt < 8; ++mt) {
                const f16x8 aw = *(const f16x8*)&Waug[(mt * 64 + lane) * 8];
                acc[0][mt] = __builtin_amdgcn_mfma_f32_16x16x32_f16(aw, xb0, acc[0][mt], 0, 0, 0);
                acc[1][mt] = __builtin_amdgcn_mfma_f32_16x16x32_f16(aw, xb1, acc[1][mt], 0, 0, 0);
            }
        }

        if (L < 4) {
            // epilogue: leaky-relu + pack; wave-private xa rows -> no barrier
            #pragma unroll
            for (int i = 0; i < 2; ++i) {
                const int pr = (pw + i * 16 + l15) * XS;
                #pragma unroll
                for (int mt = 0; mt < 8; ++mt) {
                    f16x4 hv;
                    #pragma unroll
                    for (int r = 0; r < 4; ++r) {
                        float v = acc[i][mt][r];
                        v = fmaxf(v, 0.01f * v);
                        hv[r] = (f16)v;
                    }
                    *(f16x4*)&xa[pr + mt * 16 + q * 4] = hv;
                }
            }
            if (L < 3) {   // next layer's nv into xaug (owning thread; same-wave reader)
                const int Ln = L + 1;
                if ((Ln >> 1) == h)
                    *(f16x8*)&xaug[p * AS] = (Ln & 1) ? nvb : nva;
            }
        } else {
            // head: out = tw2 . lrelu(h) + tb2; butterfly over quads
            #pragma unroll
            for (int i = 0; i < 2; ++i) {
                float s = 0.f;
                #pragma unroll
                for (int mt = 0; mt < 8; ++mt) {
                    const f32x4 w4 = *(const f32x4*)&tw2_sh[mt * 16 + q * 4];
                    #pragma unroll
                    for (int r = 0; r < 4; ++r) {
                        float v = acc[i][mt][r];
                        v = fmaxf(v, 0.01f * v);
                        s += w4[r] * v;
                    }
                }
                s += __shfl_xor(s, 16);
                s += __shfl_xor(s, 32);
                if (q == 0) out[pbase + pw + i * 16 + l15] = s + tb2_0;
            }
        }
    }
}

extern "C" void kernel_launch(void* const* d_in, const int* in_sizes, int n_in,
                              void* d_out, int out_size, void* d_ws, size_t ws_size,
                              hipStream_t stream) {
    const float* noise  = (const float*)d_in[0];
    const float* coords = (const float*)d_in[1];
    const float* trans  = (const float*)d_in[2];
    const float* ivec   = (const float*)d_in[3];
    const float* lw     = (const float*)d_in[4];
    const float* lb     = (const float*)d_in[5];
    const float* lnw    = (const float*)d_in[6];
    const float* tw1    = (const float*)d_in[7];
    const float* tb1    = (const float*)d_in[8];
    const float* tw2    = (const float*)d_in[9];
    const float* tb2    = (const float*)d_in[10];
    float* o            = (float*)d_out;

    const int N = in_sizes[1] / 2;                    // coords is [N,2]
    // ws layout: nv [32 planes][N] f16 (16 MiB) | wf | waug | quads (16 MiB)
    f16* nv    = (f16*)d_ws;
    const size_t NV = (size_t)N * 32;                 // f16 units
    f16* wfp   = nv + NV;
    f16* waugp = wfp + 5 * 16384;
    f16* qn    = waugp + 5 * 4096;
    const size_t need_full = (NV + 5 * 16384 + 5 * 4096
                              + (size_t)32 * 256 * 256 * 4) * sizeof(f16);

    if (ws_size >= need_full) {   // ws_size constant across calls -> graph-safe
        pack_all_k<<<8192 + 50, 256, 0, stream>>>(noise, qn, lw, lnw, lb, tw1, tb1,
                                                  ivec, wfp, waugp);
        sample_kernel<true><<<(N / 256) * 8, 256, 0, stream>>>(qn, coords, trans, nv, N);
    } else {
        pack_w_k<<<50, 256, 0, stream>>>(lw, lnw, lb, tw1, tb1, ivec, wfp, waugp);
        sample_kernel<false><<<(N / 256) * 8, 256, 0, stream>>>(noise, coords, trans, nv, N);
    }
    mlp_kernel<<<N / PTS, 256, 0, stream>>>(nv, wfp, waugp, tw2, tb2, o, N);
}